// Round 1
// baseline (11059.779 us; speedup 1.0000x reference)
//
#include <hip/hip_runtime.h>
#include <math.h>

#define HD 50
#define TT 512
#define BR 8        // batch rows per block
#define TC 64       // timestep chunk for x prefetch
#define HP 52       // padded row stride for h/c (16B-aligned: 52*4=208)

__device__ __forceinline__ float sigf(float x) {
    return 1.0f / (1.0f + __expf(-x));
}
__device__ __forceinline__ float tanhfast(float x) {
    // tanh(x) = 1 - 2/(exp(2x)+1); saturates correctly at +/-inf
    return 1.0f - 2.0f / (__expf(2.0f * x) + 1.0f);
}

__global__ __launch_bounds__(256, 2) void lstm2_fc_kernel(
    const float* __restrict__ x,
    const float* __restrict__ Wih0, const float* __restrict__ Whh0,
    const float* __restrict__ bih0, const float* __restrict__ bhh0,
    const float* __restrict__ Wih1, const float* __restrict__ Whh1,
    const float* __restrict__ bih1, const float* __restrict__ bhh1,
    const float* __restrict__ Wfc, const float* __restrict__ bfc,
    float* __restrict__ out)
{
    __shared__ float s_x[BR][TC * 3];
    __shared__ float s_h0[BR][HP], s_c0[BR][HP];
    __shared__ float s_h1[BR][HP], s_c1[BR][HP];
    __shared__ float s_pre[4][BR][HD];

    const int tid = threadIdx.x;
    const int w = tid >> 6;      // wave id == gate type (0=i,1=f,2=g,3=o)
    const int j = tid & 63;      // lane == hidden unit (active if < 50)
    const int r0 = blockIdx.x * BR;

    // ---- preload this lane's weight slices into VGPRs (resident all loop) ----
    float whh0[HD], wih1[HD], whh1[HD], wih0c[3];
    float b0 = 0.f, b1 = 0.f;
    if (j < HD) {
        const int g = w * HD + j;
        #pragma unroll
        for (int k = 0; k < HD; ++k) whh0[k] = Whh0[g * HD + k];
        #pragma unroll
        for (int k = 0; k < HD; ++k) wih1[k] = Wih1[g * HD + k];
        #pragma unroll
        for (int k = 0; k < HD; ++k) whh1[k] = Whh1[g * HD + k];
        wih0c[0] = Wih0[g * 3 + 0];
        wih0c[1] = Wih0[g * 3 + 1];
        wih0c[2] = Wih0[g * 3 + 2];
        b0 = bih0[g] + bhh0[g];
        b1 = bih1[g] + bhh1[g];
    }

    // ---- zero-init state ----
    for (int p = tid; p < BR * HP; p += 256) {
        (&s_h0[0][0])[p] = 0.f;
        (&s_c0[0][0])[p] = 0.f;
        (&s_h1[0][0])[p] = 0.f;
        (&s_c1[0][0])[p] = 0.f;
    }
    __syncthreads();

    for (int t = 0; t < TT; ++t) {
        const int tc = t % TC;
        if (tc == 0) {
            // stage x[r0..r0+BR-1][t..t+TC-1][0..2] -> LDS (coalesced per-row segments)
            for (int p = tid; p < BR * TC * 3; p += 256) {
                int r = p / (TC * 3);
                int q = p % (TC * 3);
                s_x[r][q] = x[(size_t)(r0 + r) * (TT * 3) + (size_t)t * 3 + q];
            }
            __syncthreads();
        }

        // ---- phase A: layer-0 gate preacts (wave w -> gate type w) ----
        if (j < HD) {
            #pragma unroll 2
            for (int r = 0; r < BR; ++r) {
                float acc = b0
                          + wih0c[0] * s_x[r][tc * 3 + 0]
                          + wih0c[1] * s_x[r][tc * 3 + 1]
                          + wih0c[2] * s_x[r][tc * 3 + 2];
                #pragma unroll
                for (int k = 0; k < HD; ++k) acc += whh0[k] * s_h0[r][k];
                s_pre[w][r][j] = acc;
            }
        }
        __syncthreads();

        // ---- phase B: layer-0 elementwise update ----
        for (int p = tid; p < BR * HD; p += 256) {
            int r = p / HD, jj = p % HD;
            float iv = sigf(s_pre[0][r][jj]);
            float fv = sigf(s_pre[1][r][jj]);
            float gv = tanhfast(s_pre[2][r][jj]);
            float ov = sigf(s_pre[3][r][jj]);
            float c = fv * s_c0[r][jj] + iv * gv;
            s_c0[r][jj] = c;
            s_h0[r][jj] = ov * tanhfast(c);
        }
        __syncthreads();

        // ---- phase C: layer-1 gate preacts ----
        if (j < HD) {
            #pragma unroll 2
            for (int r = 0; r < BR; ++r) {
                float acc = b1;
                #pragma unroll
                for (int k = 0; k < HD; ++k) acc += wih1[k] * s_h0[r][k];
                #pragma unroll
                for (int k = 0; k < HD; ++k) acc += whh1[k] * s_h1[r][k];
                s_pre[w][r][j] = acc;
            }
        }
        __syncthreads();

        // ---- phase D: layer-1 elementwise update ----
        for (int p = tid; p < BR * HD; p += 256) {
            int r = p / HD, jj = p % HD;
            float iv = sigf(s_pre[0][r][jj]);
            float fv = sigf(s_pre[1][r][jj]);
            float gv = tanhfast(s_pre[2][r][jj]);
            float ov = sigf(s_pre[3][r][jj]);
            float c = fv * s_c1[r][jj] + iv * gv;
            s_c1[r][jj] = c;
            s_h1[r][jj] = ov * tanhfast(c);
        }
        __syncthreads();
    }

    // ---- FC epilogue: out[r][o] = h1[r] . Wfc[o] + bfc[o] ----
    for (int p = tid; p < BR * 7; p += 256) {
        int r = p / 7, o = p % 7;
        float acc = bfc[o];
        #pragma unroll
        for (int k = 0; k < HD; ++k) acc += Wfc[o * HD + k] * s_h1[r][k];
        out[(size_t)(r0 + r) * 7 + o] = acc;
    }
}

extern "C" void kernel_launch(void* const* d_in, const int* in_sizes, int n_in,
                              void* d_out, int out_size, void* d_ws, size_t ws_size,
                              hipStream_t stream) {
    const float* xp    = (const float*)d_in[0];
    const float* Wih0  = (const float*)d_in[1];
    const float* Whh0  = (const float*)d_in[2];
    const float* bih0  = (const float*)d_in[3];
    const float* bhh0  = (const float*)d_in[4];
    const float* Wih1  = (const float*)d_in[5];
    const float* Whh1  = (const float*)d_in[6];
    const float* bih1  = (const float*)d_in[7];
    const float* bhh1  = (const float*)d_in[8];
    const float* Wfc   = (const float*)d_in[9];
    const float* bfc   = (const float*)d_in[10];
    float* outp = (float*)d_out;

    const int B = in_sizes[0] / (TT * 3);   // 4096
    const int grid = B / BR;                // 512 blocks, 2 per CU

    lstm2_fc_kernel<<<grid, 256, 0, stream>>>(
        xp, Wih0, Whh0, bih0, bhh0, Wih1, Whh1, bih1, bhh1, Wfc, bfc, outp);
}

// Round 2
// 4759.760 us; speedup vs baseline: 2.3236x; 2.3236x over previous
//
#include <hip/hip_runtime.h>
#include <math.h>

#define HD 50
#define TT 512
#define BR 8        // batch rows per block
#define TC 64       // timestep chunk for x prefetch
#define HP 52       // padded row stride for h/c (16B-aligned: 52*4=208)

__device__ __forceinline__ float sigf(float x) {
    return 1.0f / (1.0f + __expf(-x));
}
__device__ __forceinline__ float tanhfast(float x) {
    // tanh(x) = 1 - 2/(exp(2x)+1); saturates correctly at +/-inf
    return 1.0f - 2.0f / (__expf(2.0f * x) + 1.0f);
}

// NOTE: single-arg launch_bounds. Round-1's (256,2) capped VGPRs at 128 and
// spilled the 150-float weight arrays to scratch -> 31 GB of HBM traffic.
__global__ __launch_bounds__(256) void lstm2_fc_kernel(
    const float* __restrict__ x,
    const float* __restrict__ Wih0, const float* __restrict__ Whh0,
    const float* __restrict__ bih0, const float* __restrict__ bhh0,
    const float* __restrict__ Wih1, const float* __restrict__ Whh1,
    const float* __restrict__ bih1, const float* __restrict__ bhh1,
    const float* __restrict__ Wfc, const float* __restrict__ bfc,
    float* __restrict__ out)
{
    __shared__ float s_x[BR][TC * 3];
    __shared__ float s_h0[BR][HP], s_c0[BR][HP];
    __shared__ float s_h1[BR][HP], s_c1[BR][HP];
    __shared__ float s_pre[4][BR][HD];

    const int tid = threadIdx.x;
    const int w = tid >> 6;              // wave id == gate type (0=i,1=f,2=g,3=o)
    const int j = tid & 63;              // lane == hidden unit (active if < 50)
    const int jj = (j < HD) ? j : (HD - 1);  // clamp: lanes 50-63 duplicate lane 49
    const int g = w * HD + jj;
    const int r0 = blockIdx.x * BR;

    // ---- preload this lane's weight slices into VGPRs, UNCONDITIONALLY ----
    float whh0[HD], wih1[HD], whh1[HD];
    float wx0, wx1, wx2, b0, b1;
    #pragma unroll
    for (int k = 0; k < HD; ++k) whh0[k] = Whh0[g * HD + k];
    #pragma unroll
    for (int k = 0; k < HD; ++k) wih1[k] = Wih1[g * HD + k];
    #pragma unroll
    for (int k = 0; k < HD; ++k) whh1[k] = Whh1[g * HD + k];
    wx0 = Wih0[g * 3 + 0];
    wx1 = Wih0[g * 3 + 1];
    wx2 = Wih0[g * 3 + 2];
    b0 = bih0[g] + bhh0[g];
    b1 = bih1[g] + bhh1[g];

    // ---- zero-init state ----
    for (int p = tid; p < BR * HP; p += 256) {
        (&s_h0[0][0])[p] = 0.f;
        (&s_c0[0][0])[p] = 0.f;
        (&s_h1[0][0])[p] = 0.f;
        (&s_c1[0][0])[p] = 0.f;
    }
    __syncthreads();

    for (int t = 0; t < TT; ++t) {
        const int tc = t % TC;
        if (tc == 0) {
            // stage x[r0..r0+BR-1][t..t+TC-1][0..2] -> LDS
            for (int p = tid; p < BR * TC * 3; p += 256) {
                int r = p / (TC * 3);
                int q = p % (TC * 3);
                s_x[r][q] = x[(size_t)(r0 + r) * (TT * 3) + (size_t)t * 3 + q];
            }
            __syncthreads();
        }

        // ---- phase A: layer-0 gate preacts (wave w -> gate type w) ----
        {
            #pragma unroll 2
            for (int r = 0; r < BR; ++r) {
                float a = b0
                        + wx0 * s_x[r][tc * 3 + 0]
                        + wx1 * s_x[r][tc * 3 + 1]
                        + wx2 * s_x[r][tc * 3 + 2];
                #pragma unroll
                for (int k = 0; k < HD; ++k) a += whh0[k] * s_h0[r][k];
                if (j < HD) s_pre[w][r][j] = a;
            }
        }
        __syncthreads();

        // ---- phase B: layer-0 elementwise update ----
        for (int p = tid; p < BR * HD; p += 256) {
            int r = p / HD, q = p % HD;
            float iv = sigf(s_pre[0][r][q]);
            float fv = sigf(s_pre[1][r][q]);
            float gv = tanhfast(s_pre[2][r][q]);
            float ov = sigf(s_pre[3][r][q]);
            float c = fv * s_c0[r][q] + iv * gv;
            s_c0[r][q] = c;
            s_h0[r][q] = ov * tanhfast(c);
        }
        __syncthreads();

        // ---- phase C: layer-1 gate preacts (two independent chains per row) ----
        {
            #pragma unroll 2
            for (int r = 0; r < BR; ++r) {
                float a  = b1;
                float a2 = 0.f;
                #pragma unroll
                for (int k = 0; k < HD; ++k) {
                    a  += wih1[k] * s_h0[r][k];
                    a2 += whh1[k] * s_h1[r][k];
                }
                if (j < HD) s_pre[w][r][j] = a + a2;
            }
        }
        __syncthreads();

        // ---- phase D: layer-1 elementwise update ----
        for (int p = tid; p < BR * HD; p += 256) {
            int r = p / HD, q = p % HD;
            float iv = sigf(s_pre[0][r][q]);
            float fv = sigf(s_pre[1][r][q]);
            float gv = tanhfast(s_pre[2][r][q]);
            float ov = sigf(s_pre[3][r][q]);
            float c = fv * s_c1[r][q] + iv * gv;
            s_c1[r][q] = c;
            s_h1[r][q] = ov * tanhfast(c);
        }
        __syncthreads();
    }

    // ---- FC epilogue: out[r][o] = h1[r] . Wfc[o] + bfc[o] ----
    for (int p = tid; p < BR * 7; p += 256) {
        int r = p / 7, o = p % 7;
        float acc = bfc[o];
        #pragma unroll
        for (int k = 0; k < HD; ++k) acc += Wfc[o * HD + k] * s_h1[r][k];
        out[(size_t)(r0 + r) * 7 + o] = acc;
    }
}

extern "C" void kernel_launch(void* const* d_in, const int* in_sizes, int n_in,
                              void* d_out, int out_size, void* d_ws, size_t ws_size,
                              hipStream_t stream) {
    const float* xp    = (const float*)d_in[0];
    const float* Wih0  = (const float*)d_in[1];
    const float* Whh0  = (const float*)d_in[2];
    const float* bih0  = (const float*)d_in[3];
    const float* bhh0  = (const float*)d_in[4];
    const float* Wih1  = (const float*)d_in[5];
    const float* Whh1  = (const float*)d_in[6];
    const float* bih1  = (const float*)d_in[7];
    const float* bhh1  = (const float*)d_in[8];
    const float* Wfc   = (const float*)d_in[9];
    const float* bfc   = (const float*)d_in[10];
    float* outp = (float*)d_out;

    const int B = in_sizes[0] / (TT * 3);   // 4096
    const int grid = B / BR;                // 512 blocks

    lstm2_fc_kernel<<<grid, 256, 0, stream>>>(
        xp, Wih0, Whh0, bih0, bhh0, Wih1, Whh1, bih1, bhh1, Wfc, bfc, outp);
}